// Round 2
// baseline (1138.247 us; speedup 1.0000x reference)
//
#include <hip/hip_runtime.h>
#include <cmath>

// Problem constants (from reference setup_inputs):
//   xfb: (N=64, B=16, C=22, T=4000) fp32
//   WT : (B=16, M=16, C=22) fp32
//   out: (N, B, M) fp32 = log(diag / sum_m diag), diag = sum_t (W.x)^2
// The 1/sqrt(T) scaling cancels in the ratio -> skipped.

#define N_ 64
#define B_ 16
#define C_ 22
#define T_ 4000
#define M_ 16

__global__ __launch_bounds__(256, 2)
void OVR_CSP_kernel(const float* __restrict__ xfb,
                    const float* __restrict__ WT,
                    float* __restrict__ out) {
    const int bid = blockIdx.x;        // n*B + b
    const int b   = bid & (B_ - 1);
    const int tid = threadIdx.x;

    __shared__ float wsh[M_ * C_];     // W[b]: 16x22 = 352 floats
    __shared__ float red[4][M_];       // per-wave partials
    __shared__ float dsh[M_];          // final diag

    // BUG FIX (R1): M_*C_ = 352 > blockDim 256 — must stride, or wsh[256..351]
    // is stale LDS garbage (corrupted diag[11..15] and the total last round).
    for (int i = tid; i < M_ * C_; i += 256)
        wsh[i] = WT[b * (M_ * C_) + i];
    __syncthreads();

    const float* __restrict__ xb = xfb + (size_t)bid * (C_ * T_);

    float acc[M_];
    #pragma unroll
    for (int m = 0; m < M_; ++m) acc[m] = 0.f;

    const int J = T_ / 4;              // 1000 float4 columns
    for (int j = tid; j < J; j += 256) {
        float4 xv[C_];
        #pragma unroll
        for (int c = 0; c < C_; ++c)
            xv[c] = *(const float4*)(xb + c * T_ + 4 * j);

        #pragma unroll
        for (int m = 0; m < M_; ++m) {
            float4 d = make_float4(0.f, 0.f, 0.f, 0.f);
            #pragma unroll
            for (int c = 0; c < C_; ++c) {
                const float w = wsh[m * C_ + c];
                d.x = fmaf(w, xv[c].x, d.x);
                d.y = fmaf(w, xv[c].y, d.y);
                d.z = fmaf(w, xv[c].z, d.z);
                d.w = fmaf(w, xv[c].w, d.w);
            }
            acc[m] += d.x * d.x + d.y * d.y + d.z * d.z + d.w * d.w;
        }
    }

    // wave-level reduction (wave = 64 lanes on gfx950)
    #pragma unroll
    for (int m = 0; m < M_; ++m) {
        float v = acc[m];
        #pragma unroll
        for (int off = 32; off > 0; off >>= 1)
            v += __shfl_down(v, off, 64);
        acc[m] = v;
    }

    const int wave = tid >> 6;
    const int lane = tid & 63;
    if (lane == 0) {
        #pragma unroll
        for (int m = 0; m < M_; ++m) red[wave][m] = acc[m];
    }
    __syncthreads();

    if (tid < M_) {
        dsh[tid] = red[0][tid] + red[1][tid] + red[2][tid] + red[3][tid];
    }
    __syncthreads();

    if (tid < M_) {
        float total = 0.f;
        #pragma unroll
        for (int m = 0; m < M_; ++m) total += dsh[m];
        out[(size_t)bid * M_ + tid] = logf(dsh[tid] / total);
    }
}

extern "C" void kernel_launch(void* const* d_in, const int* in_sizes, int n_in,
                              void* d_out, int out_size, void* d_ws, size_t ws_size,
                              hipStream_t stream) {
    const float* xfb = (const float*)d_in[0];
    const float* WT  = (const float*)d_in[1];
    float* out = (float*)d_out;

    dim3 grid(N_ * B_);   // 1024 blocks, one per (n,b)
    dim3 block(256);
    OVR_CSP_kernel<<<grid, block, 0, stream>>>(xfb, WT, out);
}

// Round 3
// 1046.332 us; speedup vs baseline: 1.0878x; 1.0878x over previous
//
#include <hip/hip_runtime.h>
#include <cmath>

// xfb: (N=64, B=16, C=22, T=4000) fp32; WT: (B=16, M=16, C=22) fp32
// out[n,b,m] = log(diag / sum_m diag), diag = sum_t (W.x)^2 ; 1/sqrt(T) cancels.
//
// R2 post-mortem: xv[22] float4 (88 VGPRs) spilled to scratch at VGPR=128 ->
// 442 MB scratch writes, 4x overfetch, 765 us latency-bound. R3: hold d[16]
// float4 dot accumulators instead (64 VGPRs), stream x 4 channels at a time,
// re-read W from LDS via ds_read_b128 (rows padded to 24 floats = 96 B for
// 16-B alignment). Peak live regs ~112 -> no spill.

#define N_ 64
#define B_ 16
#define C_ 22
#define T_ 4000
#define M_ 16
#define CP_ 24   // padded row stride for W in LDS (16-B aligned rows)

__global__ __launch_bounds__(256, 2)
void OVR_CSP_kernel(const float* __restrict__ xfb,
                    const float* __restrict__ WT,
                    float* __restrict__ out) {
    const int bid = blockIdx.x;        // n*B + b
    const int b   = bid & (B_ - 1);
    const int tid = threadIdx.x;

    __shared__ __align__(16) float wsh[M_ * CP_];  // 16 rows x 24 floats
    __shared__ float red[4][M_];
    __shared__ float dsh[M_];

    // stage W[b] with padding (zero the pad lanes)
    for (int i = tid; i < M_ * CP_; i += 256) {
        const int m = i / CP_, c = i - m * CP_;
        wsh[i] = (c < C_) ? WT[b * (M_ * C_) + m * C_ + c] : 0.f;
    }
    __syncthreads();

    const float* __restrict__ xb = xfb + (size_t)bid * (C_ * T_);

    float acc[M_];
    #pragma unroll
    for (int m = 0; m < M_; ++m) acc[m] = 0.f;

    const int J = T_ / 4;              // 1000 float4 columns
    for (int j = tid; j < J; j += 256) {
        const float* xj = xb + 4 * j;

        float4 d[M_];
        #pragma unroll
        for (int m = 0; m < M_; ++m) d[m] = make_float4(0.f, 0.f, 0.f, 0.f);

        // 5 full channel-groups of 4 (c = 0..19)
        #pragma unroll
        for (int g = 0; g < 5; ++g) {
            const float4 x0 = *(const float4*)(xj + (4 * g + 0) * T_);
            const float4 x1 = *(const float4*)(xj + (4 * g + 1) * T_);
            const float4 x2 = *(const float4*)(xj + (4 * g + 2) * T_);
            const float4 x3 = *(const float4*)(xj + (4 * g + 3) * T_);
            #pragma unroll
            for (int m = 0; m < M_; ++m) {
                const float4 wv = *(const float4*)&wsh[m * CP_ + 4 * g];
                d[m].x = fmaf(wv.x, x0.x, d[m].x);
                d[m].y = fmaf(wv.x, x0.y, d[m].y);
                d[m].z = fmaf(wv.x, x0.z, d[m].z);
                d[m].w = fmaf(wv.x, x0.w, d[m].w);
                d[m].x = fmaf(wv.y, x1.x, d[m].x);
                d[m].y = fmaf(wv.y, x1.y, d[m].y);
                d[m].z = fmaf(wv.y, x1.z, d[m].z);
                d[m].w = fmaf(wv.y, x1.w, d[m].w);
                d[m].x = fmaf(wv.z, x2.x, d[m].x);
                d[m].y = fmaf(wv.z, x2.y, d[m].y);
                d[m].z = fmaf(wv.z, x2.z, d[m].z);
                d[m].w = fmaf(wv.z, x2.w, d[m].w);
                d[m].x = fmaf(wv.w, x3.x, d[m].x);
                d[m].y = fmaf(wv.w, x3.y, d[m].y);
                d[m].z = fmaf(wv.w, x3.z, d[m].z);
                d[m].w = fmaf(wv.w, x3.w, d[m].w);
            }
        }
        // tail channels c = 20, 21
        {
            const float4 x0 = *(const float4*)(xj + 20 * T_);
            const float4 x1 = *(const float4*)(xj + 21 * T_);
            #pragma unroll
            for (int m = 0; m < M_; ++m) {
                const float2 wv = *(const float2*)&wsh[m * CP_ + 20];
                d[m].x = fmaf(wv.x, x0.x, d[m].x);
                d[m].y = fmaf(wv.x, x0.y, d[m].y);
                d[m].z = fmaf(wv.x, x0.z, d[m].z);
                d[m].w = fmaf(wv.x, x0.w, d[m].w);
                d[m].x = fmaf(wv.y, x1.x, d[m].x);
                d[m].y = fmaf(wv.y, x1.y, d[m].y);
                d[m].z = fmaf(wv.y, x1.z, d[m].z);
                d[m].w = fmaf(wv.y, x1.w, d[m].w);
            }
        }

        #pragma unroll
        for (int m = 0; m < M_; ++m)
            acc[m] += d[m].x * d[m].x + d[m].y * d[m].y +
                      d[m].z * d[m].z + d[m].w * d[m].w;
    }

    // wave reduction (wave = 64)
    #pragma unroll
    for (int m = 0; m < M_; ++m) {
        float v = acc[m];
        #pragma unroll
        for (int off = 32; off > 0; off >>= 1)
            v += __shfl_down(v, off, 64);
        acc[m] = v;
    }

    const int wave = tid >> 6;
    const int lane = tid & 63;
    if (lane == 0) {
        #pragma unroll
        for (int m = 0; m < M_; ++m) red[wave][m] = acc[m];
    }
    __syncthreads();

    if (tid < M_)
        dsh[tid] = red[0][tid] + red[1][tid] + red[2][tid] + red[3][tid];
    __syncthreads();

    if (tid < M_) {
        float total = 0.f;
        #pragma unroll
        for (int m = 0; m < M_; ++m) total += dsh[m];
        out[(size_t)bid * M_ + tid] = logf(dsh[tid] / total);
    }
}

extern "C" void kernel_launch(void* const* d_in, const int* in_sizes, int n_in,
                              void* d_out, int out_size, void* d_ws, size_t ws_size,
                              hipStream_t stream) {
    const float* xfb = (const float*)d_in[0];
    const float* WT  = (const float*)d_in[1];
    float* out = (float*)d_out;

    dim3 grid(N_ * B_);   // 1024 blocks, one per (n,b)
    dim3 block(256);
    OVR_CSP_kernel<<<grid, block, 0, stream>>>(xfb, WT, out);
}

// Round 4
// 798.011 us; speedup vs baseline: 1.4264x; 1.3112x over previous
//
#include <hip/hip_runtime.h>
#include <cmath>

// xfb: (N=64, B=16, C=22, T=4000) fp32; WT: (B=16, M=16, C=22) fp32
// out[n,b,m] = log(diag / sum_m diag), diag = sum_t (W.x)^2 ; 1/sqrt(T) cancels.
//
// R3 post-mortem: still spilling (WRITE 620 MB, FETCH 4x). Root cause: loads
// written as (per-thread ptr xj) + c*T_ -> ~22 live 64-bit per-thread pointer
// pairs (~40 VGPRs) + d[16]f4 (64) + acc (16) > 128 budget -> scratch.
// R4 fix: (a) uniform-base + 32-bit per-thread offset addressing so the
// compiler emits saddr-form loads (one offset VGPR total); (b) launch_bounds
// min-waves=1 so the allocator takes ~160 VGPRs instead of spilling.

#define N_ 64
#define B_ 16
#define C_ 22
#define T_ 4000
#define M_ 16
#define CP_ 24   // padded row stride for W in LDS (16-B aligned rows)

__global__ __launch_bounds__(256, 1)
void OVR_CSP_kernel(const float* __restrict__ xfb,
                    const float* __restrict__ WT,
                    float* __restrict__ out) {
    const int bid = blockIdx.x;        // n*B + b
    const int b   = bid & (B_ - 1);
    const int tid = threadIdx.x;

    __shared__ __align__(16) float wsh[M_ * CP_];  // 16 rows x 24 floats
    __shared__ float red[4][M_];
    __shared__ float dsh[M_];

    for (int i = tid; i < M_ * CP_; i += 256) {
        const int m = i / CP_, c = i - m * CP_;
        wsh[i] = (c < C_) ? WT[b * (M_ * C_) + m * C_ + c] : 0.f;
    }
    __syncthreads();

    // Block-uniform base pointer; all per-thread variation goes through a
    // single 32-bit element offset so loads compile to saddr + voffset form.
    const float* __restrict__ xb = xfb + (size_t)bid * (C_ * T_);

    float acc[M_];
    #pragma unroll
    for (int m = 0; m < M_; ++m) acc[m] = 0.f;

    const int J = T_ / 4;              // 1000 float4 columns
    for (int j = tid; j < J; j += 256) {
        const int off = 4 * j;         // per-thread 32-bit element offset

        float4 d[M_];
        #pragma unroll
        for (int m = 0; m < M_; ++m) d[m] = make_float4(0.f, 0.f, 0.f, 0.f);

        // 5 full channel-groups of 4 (c = 0..19); uniform base = xb + c*T_
        #pragma unroll
        for (int g = 0; g < 5; ++g) {
            const float4 x0 = *(const float4*)(xb + (4 * g + 0) * T_ + off);
            const float4 x1 = *(const float4*)(xb + (4 * g + 1) * T_ + off);
            const float4 x2 = *(const float4*)(xb + (4 * g + 2) * T_ + off);
            const float4 x3 = *(const float4*)(xb + (4 * g + 3) * T_ + off);
            #pragma unroll
            for (int m = 0; m < M_; ++m) {
                const float4 wv = *(const float4*)&wsh[m * CP_ + 4 * g];
                d[m].x = fmaf(wv.x, x0.x, d[m].x);
                d[m].y = fmaf(wv.x, x0.y, d[m].y);
                d[m].z = fmaf(wv.x, x0.z, d[m].z);
                d[m].w = fmaf(wv.x, x0.w, d[m].w);
                d[m].x = fmaf(wv.y, x1.x, d[m].x);
                d[m].y = fmaf(wv.y, x1.y, d[m].y);
                d[m].z = fmaf(wv.y, x1.z, d[m].z);
                d[m].w = fmaf(wv.y, x1.w, d[m].w);
                d[m].x = fmaf(wv.z, x2.x, d[m].x);
                d[m].y = fmaf(wv.z, x2.y, d[m].y);
                d[m].z = fmaf(wv.z, x2.z, d[m].z);
                d[m].w = fmaf(wv.z, x2.w, d[m].w);
                d[m].x = fmaf(wv.w, x3.x, d[m].x);
                d[m].y = fmaf(wv.w, x3.y, d[m].y);
                d[m].z = fmaf(wv.w, x3.z, d[m].z);
                d[m].w = fmaf(wv.w, x3.w, d[m].w);
            }
        }
        // tail channels c = 20, 21
        {
            const float4 x0 = *(const float4*)(xb + 20 * T_ + off);
            const float4 x1 = *(const float4*)(xb + 21 * T_ + off);
            #pragma unroll
            for (int m = 0; m < M_; ++m) {
                const float2 wv = *(const float2*)&wsh[m * CP_ + 20];
                d[m].x = fmaf(wv.x, x0.x, d[m].x);
                d[m].y = fmaf(wv.x, x0.y, d[m].y);
                d[m].z = fmaf(wv.x, x0.z, d[m].z);
                d[m].w = fmaf(wv.x, x0.w, d[m].w);
                d[m].x = fmaf(wv.y, x1.x, d[m].x);
                d[m].y = fmaf(wv.y, x1.y, d[m].y);
                d[m].z = fmaf(wv.y, x1.z, d[m].z);
                d[m].w = fmaf(wv.y, x1.w, d[m].w);
            }
        }

        #pragma unroll
        for (int m = 0; m < M_; ++m)
            acc[m] += d[m].x * d[m].x + d[m].y * d[m].y +
                      d[m].z * d[m].z + d[m].w * d[m].w;
    }

    // wave reduction (wave = 64)
    #pragma unroll
    for (int m = 0; m < M_; ++m) {
        float v = acc[m];
        #pragma unroll
        for (int off = 32; off > 0; off >>= 1)
            v += __shfl_down(v, off, 64);
        acc[m] = v;
    }

    const int wave = tid >> 6;
    const int lane = tid & 63;
    if (lane == 0) {
        #pragma unroll
        for (int m = 0; m < M_; ++m) red[wave][m] = acc[m];
    }
    __syncthreads();

    if (tid < M_)
        dsh[tid] = red[0][tid] + red[1][tid] + red[2][tid] + red[3][tid];
    __syncthreads();

    if (tid < M_) {
        float total = 0.f;
        #pragma unroll
        for (int m = 0; m < M_; ++m) total += dsh[m];
        out[(size_t)bid * M_ + tid] = logf(dsh[tid] / total);
    }
}

extern "C" void kernel_launch(void* const* d_in, const int* in_sizes, int n_in,
                              void* d_out, int out_size, void* d_ws, size_t ws_size,
                              hipStream_t stream) {
    const float* xfb = (const float*)d_in[0];
    const float* WT  = (const float*)d_in[1];
    float* out = (float*)d_out;

    dim3 grid(N_ * B_);   // 1024 blocks, one per (n,b)
    dim3 block(256);
    OVR_CSP_kernel<<<grid, block, 0, stream>>>(xfb, WT, out);
}